// Round 1
// baseline (123.879 us; speedup 1.0000x reference)
//
#include <hip/hip_runtime.h>

#define DEV __device__ __forceinline__

typedef __bf16 bf16;
typedef __bf16 bf16x8 __attribute__((ext_vector_type(8)));
typedef float f32x4 __attribute__((ext_vector_type(4)));

#define B_ 2
#define D_ 512
#define N_ 2048
#define H_ 8
#define MD_ 64
#define SCALE_F 0.04419417382415922f  /* 1/sqrt(512) */

DEV void gload_lds16(const void* g, void* l) {
  __builtin_amdgcn_global_load_lds(
      (const __attribute__((address_space(1))) void*)g,
      (__attribute__((address_space(3))) void*)l, 16, 0, 0);
}

DEV f32x4 mfma16(bf16x8 a, bf16x8 b, f32x4 c) {
  return __builtin_amdgcn_mfma_f32_16x16x32_bf16(a, b, c, 0, 0, 0);
}

// ---------------------------------------------------------------------------
// prep_w: rows 0..1535 -> Wf bf16 (Wq*SCALE | Wk | Wv), bias_f (bq*SCALE|bk|bv)
//         rows 1536..2047 -> Wo_r[r][h*64+d] = Wo[r][d*8+h]  (bf16)
// ---------------------------------------------------------------------------
__global__ __launch_bounds__(256) void prep_w(
    const float* __restrict__ Wq, const float* __restrict__ bq,
    const float* __restrict__ Wk, const float* __restrict__ bk,
    const float* __restrict__ Wv, const float* __restrict__ bv,
    const float* __restrict__ Wo,
    bf16* __restrict__ Wf, float* __restrict__ biasf, bf16* __restrict__ Wor) {
  int row = blockIdx.x;
  int t = threadIdx.x;
  if (row < 1536) {
    const float* src;
    float scale = 1.0f;
    if (row < 512)       { src = Wq + (size_t)row * 512; scale = SCALE_F; }
    else if (row < 1024) { src = Wk + (size_t)(row - 512) * 512; }
    else                 { src = Wv + (size_t)(row - 1024) * 512; }
    for (int c = t; c < 512; c += 256)
      Wf[(size_t)row * 512 + c] = (bf16)(src[c] * scale);
    if (t == 0) {
      float bb;
      if (row < 512)       bb = bq[row] * SCALE_F;
      else if (row < 1024) bb = bk[row - 512];
      else                 bb = bv[row - 1024];
      biasf[row] = bb;
    }
  } else {
    int r = row - 1536;
    for (int c2 = t; c2 < 512; c2 += 256) {
      int hh = c2 >> 6, dd = c2 & 63;
      Wor[(size_t)r * 512 + c2] = (bf16)Wo[(size_t)r * 512 + dd * 8 + hh];
    }
  }
}

// ---------------------------------------------------------------------------
// prep_qt: Qt[b][n][c] = bf16(Q[b][c][n])   (64x64 tiles through LDS)
// grid (N/64, D/64, B), block 256
// ---------------------------------------------------------------------------
__global__ __launch_bounds__(256) void prep_qt(const float* __restrict__ Q,
                                               bf16* __restrict__ Qt) {
  __shared__ float tile[64][65];
  int b = blockIdx.z;
  int d0 = blockIdx.y * 64;
  int n0 = blockIdx.x * 64;
  int t = threadIdx.x;
  int r = t >> 2, cw = t & 3;

  const float* src = Q + ((size_t)(b * 512 + d0 + r)) * 2048 + n0 + cw * 16;
#pragma unroll
  for (int e4 = 0; e4 < 4; ++e4) {
    float4 v = *(const float4*)(src + e4 * 4);
    tile[r][cw * 16 + e4 * 4 + 0] = v.x;
    tile[r][cw * 16 + e4 * 4 + 1] = v.y;
    tile[r][cw * 16 + e4 * 4 + 2] = v.z;
    tile[r][cw * 16 + e4 * 4 + 3] = v.w;
  }
  __syncthreads();
  bf16x8 o0{}, o1{};
#pragma unroll
  for (int e = 0; e < 8; ++e) {
    o0[e] = (bf16)tile[cw * 16 + e][r];
    o1[e] = (bf16)tile[cw * 16 + 8 + e][r];
  }
  bf16* dst = Qt + ((size_t)(b * 2048 + n0 + r)) * 512 + d0 + cw * 16;
  *(bf16x8*)dst = o0;
  *((bf16x8*)dst + 1) = o1;
}

// ---------------------------------------------------------------------------
// qkv_gemm: C[c][p] = sum_k Wf[c][k] * Qt[b][p][k] + bias[c]
// 128x128 tile, BK=32, 4 waves (2x2), 4x4 frags/wave, global_load_lds staging.
// Epilogue: c<512 -> qp[b][h][p][d]; c<1024 -> kp; else vn[b][c][p]
// grid (12, 16, 2)
// ---------------------------------------------------------------------------
__global__ __launch_bounds__(256) void qkv_gemm(
    const bf16* __restrict__ Wf, const bf16* __restrict__ Qt,
    const float* __restrict__ biasf,
    bf16* __restrict__ qp, bf16* __restrict__ kp, bf16* __restrict__ vn) {
  __shared__ bf16 Al[128 * 32];
  __shared__ bf16 Bl[128 * 32];
  int b = blockIdx.z;
  int c0 = blockIdx.x * 128;
  int p0 = blockIdx.y * 128;
  int tid = threadIdx.x, w = tid >> 6, lane = tid & 63;
  int wm = w >> 1, wn = w & 1;
  int g = lane >> 4, l15 = lane & 15;

  const bf16* Abase = Wf + (size_t)c0 * 512;
  const bf16* Bbase = Qt + ((size_t)b * 2048 + p0) * 512;

  f32x4 acc[4][4] = {};

  for (int ks = 0; ks < 16; ++ks) {
    int k0 = ks * 32;
    __syncthreads();
#pragma unroll
    for (int i = 0; i < 2; ++i) {
      int rowl = w * 32 + i * 16 + (lane >> 2);
      int ch = lane & 3;
      gload_lds16(Abase + (size_t)rowl * 512 + k0 + ch * 8,
                  Al + (w * 32 + i * 16) * 32);
      gload_lds16(Bbase + (size_t)rowl * 512 + k0 + ch * 8,
                  Bl + (w * 32 + i * 16) * 32);
    }
    __syncthreads();
    bf16x8 a[4], bb[4];
#pragma unroll
    for (int mi = 0; mi < 4; ++mi)
      a[mi] = *(const bf16x8*)(Al + (wm * 64 + mi * 16 + l15) * 32 + g * 8);
#pragma unroll
    for (int ni = 0; ni < 4; ++ni)
      bb[ni] = *(const bf16x8*)(Bl + (wn * 64 + ni * 16 + l15) * 32 + g * 8);
#pragma unroll
    for (int mi = 0; mi < 4; ++mi)
#pragma unroll
      for (int ni = 0; ni < 4; ++ni)
        acc[mi][ni] = mfma16(a[mi], bb[ni], acc[mi][ni]);
  }

#pragma unroll
  for (int mi = 0; mi < 4; ++mi) {
#pragma unroll
    for (int ni = 0; ni < 4; ++ni) {
#pragma unroll
      for (int r = 0; r < 4; ++r) {
        int row = c0 + wm * 64 + mi * 16 + g * 4 + r;
        int p = p0 + wn * 64 + ni * 16 + l15;
        float val = acc[mi][ni][r] + biasf[row];
        bf16 hv = (bf16)val;
        if (row < 512) {
          int c = row;
          qp[(((size_t)b * 8 + (c & 7)) * 2048 + p) * 64 + (c >> 3)] = hv;
        } else if (row < 1024) {
          int c = row - 512;
          kp[(((size_t)b * 8 + (c & 7)) * 2048 + p) * 64 + (c >> 3)] = hv;
        } else {
          int c = row - 1024;
          vn[((size_t)b * 512 + c) * 2048 + p] = hv;
        }
      }
    }
  }
}

// ---------------------------------------------------------------------------
// attn_k: flash attention per (b,h). Block = 64 queries, 4 waves (16 rows each).
// KV steps of 64. All LDS tiles 64x64 bf16 (128B rows), XOR-16B-chunk swizzled.
// grid (32, 8, 2)
// ---------------------------------------------------------------------------
__global__ __launch_bounds__(256) void attn_k(
    const bf16* __restrict__ qp, const bf16* __restrict__ kp,
    const bf16* __restrict__ vn, bf16* __restrict__ oh) {
  __shared__ bf16 Qs[64 * 64];
  __shared__ bf16 Ks[64 * 64];
  __shared__ bf16 Vs[64 * 64];
  __shared__ bf16 Ps[64 * 64];
  int b = blockIdx.z, h = blockIdx.y;
  int q0 = blockIdx.x * 64;
  int tid = threadIdx.x, w = tid >> 6, lane = tid & 63;
  int g = lane >> 4, l15 = lane & 15;
  const size_t bh = (size_t)b * 8 + h;

  // stage Q once (swizzled source, linear LDS dest)
  const bf16* Qbase = qp + (bh * 2048 + q0) * 64;
#pragma unroll
  for (int i = 0; i < 2; ++i) {
    int row = w * 16 + i * 8 + (lane >> 3);
    int ch = (lane & 7) ^ (row & 7);
    gload_lds16(Qbase + (size_t)row * 64 + ch * 8, Qs + (w * 16 + i * 8) * 64);
  }

  f32x4 oacc[4] = {};
  float mrow[4], lrow[4];
#pragma unroll
  for (int r = 0; r < 4; ++r) { mrow[r] = -1e30f; lrow[r] = 0.0f; }

  int irow = w * 16 + l15;

  for (int t = 0; t < 32; ++t) {
    __syncthreads();  // previous step's LDS reads done
    const bf16* Kbase = kp + (bh * 2048 + (size_t)t * 64) * 64;
    const bf16* Vbase = vn + ((size_t)(b * 512 + h)) * 2048 + t * 64;
#pragma unroll
    for (int i = 0; i < 2; ++i) {
      int row = w * 16 + i * 8 + (lane >> 3);
      int ch = (lane & 7) ^ (row & 7);
      gload_lds16(Kbase + (size_t)row * 64 + ch * 8, Ks + (w * 16 + i * 8) * 64);
      gload_lds16(Vbase + (size_t)row * 16384 + ch * 8, Vs + (w * 16 + i * 8) * 64);
    }
    __syncthreads();  // staging (vmcnt) drained

    // S = Q K^T for this wave's 16-row strip (scale pre-folded into q)
    f32x4 s[4] = {};
#pragma unroll
    for (int ks2 = 0; ks2 < 2; ++ks2) {
      bf16x8 qa = *(const bf16x8*)(Qs + irow * 64 + (((ks2 * 4 + g) ^ (irow & 7)) << 3));
#pragma unroll
      for (int jt = 0; jt < 4; ++jt) {
        int jrow = jt * 16 + l15;
        bf16x8 kb = *(const bf16x8*)(Ks + jrow * 64 + (((ks2 * 4 + g) ^ (jrow & 7)) << 3));
        s[jt] = mfma16(qa, kb, s[jt]);
      }
    }

    // online softmax (rows = g*4+r; reduce across the 16-lane column group)
    float esc[4], rs[4];
#pragma unroll
    for (int r = 0; r < 4; ++r) {
      float rm = fmaxf(fmaxf(s[0][r], s[1][r]), fmaxf(s[2][r], s[3][r]));
      rm = fmaxf(rm, __shfl_xor(rm, 1));
      rm = fmaxf(rm, __shfl_xor(rm, 2));
      rm = fmaxf(rm, __shfl_xor(rm, 4));
      rm = fmaxf(rm, __shfl_xor(rm, 8));
      float mn = fmaxf(mrow[r], rm);
      esc[r] = __expf(mrow[r] - mn);
      mrow[r] = mn;
      lrow[r] *= esc[r];
      rs[r] = 0.0f;
    }
#pragma unroll
    for (int dt = 0; dt < 4; ++dt) {
#pragma unroll
      for (int r = 0; r < 4; ++r) oacc[dt][r] *= esc[r];
    }
#pragma unroll
    for (int jt = 0; jt < 4; ++jt) {
#pragma unroll
      for (int r = 0; r < 4; ++r) {
        float pv = __expf(s[jt][r] - mrow[r]);
        rs[r] += pv;
        int iw = w * 16 + g * 4 + r;
        int j = jt * 16 + l15;
        Ps[iw * 64 + (j ^ ((iw & 7) << 3))] = (bf16)pv;
      }
    }
#pragma unroll
    for (int r = 0; r < 4; ++r) {
      float t2 = rs[r];
      t2 += __shfl_xor(t2, 1);
      t2 += __shfl_xor(t2, 2);
      t2 += __shfl_xor(t2, 4);
      t2 += __shfl_xor(t2, 8);
      lrow[r] += t2;
    }

    // O += P V   (A = P rows, B = Vs[d][j], k = j)
#pragma unroll
    for (int ks2 = 0; ks2 < 2; ++ks2) {
      bf16x8 pa = *(const bf16x8*)(Ps + irow * 64 + (((ks2 * 4 + g) ^ (irow & 7)) << 3));
#pragma unroll
      for (int dt = 0; dt < 4; ++dt) {
        int drow = dt * 16 + l15;
        bf16x8 vb = *(const bf16x8*)(Vs + drow * 64 + (((ks2 * 4 + g) ^ (drow & 7)) << 3));
        oacc[dt] = mfma16(pa, vb, oacc[dt]);
      }
    }
  }

  // epilogue: normalize and store oh[b][h][p][d]
#pragma unroll
  for (int dt = 0; dt < 4; ++dt) {
#pragma unroll
    for (int r = 0; r < 4; ++r) {
      int i = w * 16 + g * 4 + r;
      float inv = 1.0f / lrow[r];
      oh[(bh * 2048 + q0 + i) * 64 + dt * 16 + l15] = (bf16)(oacc[dt][r] * inv);
    }
  }
}

// ---------------------------------------------------------------------------
// out_gemm: out[b][r][p] = sum_k Wor[r][k] * oh_as_B[p][k] + bo[r]   (fp32 out)
// k = h*64+d ; B row p slice for k-step lives at oh[b][h][p0+row][d0..d0+31]
// grid (4, 16, 2)
// ---------------------------------------------------------------------------
__global__ __launch_bounds__(256) void out_gemm(
    const bf16* __restrict__ Wor, const bf16* __restrict__ oh,
    const float* __restrict__ bo, float* __restrict__ out) {
  __shared__ bf16 Al[128 * 32];
  __shared__ bf16 Bl[128 * 32];
  int b = blockIdx.z;
  int r0 = blockIdx.x * 128;
  int p0 = blockIdx.y * 128;
  int tid = threadIdx.x, w = tid >> 6, lane = tid & 63;
  int wm = w >> 1, wn = w & 1;
  int g = lane >> 4, l15 = lane & 15;

  const bf16* Abase = Wor + (size_t)r0 * 512;

  f32x4 acc[4][4] = {};

  for (int ks = 0; ks < 16; ++ks) {
    int k0 = ks * 32;
    int hh = k0 >> 6, d0 = k0 & 63;
    const bf16* Bbase = oh + (((size_t)b * 8 + hh) * 2048 + p0) * 64 + d0;
    __syncthreads();
#pragma unroll
    for (int i = 0; i < 2; ++i) {
      int rowl = w * 32 + i * 16 + (lane >> 2);
      int ch = lane & 3;
      gload_lds16(Abase + (size_t)rowl * 512 + k0 + ch * 8,
                  Al + (w * 32 + i * 16) * 32);
      gload_lds16(Bbase + (size_t)rowl * 64 + ch * 8,
                  Bl + (w * 32 + i * 16) * 32);
    }
    __syncthreads();
    bf16x8 a[4], bb[4];
#pragma unroll
    for (int mi = 0; mi < 4; ++mi)
      a[mi] = *(const bf16x8*)(Al + (wm * 64 + mi * 16 + l15) * 32 + g * 8);
#pragma unroll
    for (int ni = 0; ni < 4; ++ni)
      bb[ni] = *(const bf16x8*)(Bl + (wn * 64 + ni * 16 + l15) * 32 + g * 8);
#pragma unroll
    for (int mi = 0; mi < 4; ++mi)
#pragma unroll
      for (int ni = 0; ni < 4; ++ni)
        acc[mi][ni] = mfma16(a[mi], bb[ni], acc[mi][ni]);
  }

#pragma unroll
  for (int mi = 0; mi < 4; ++mi) {
#pragma unroll
    for (int ni = 0; ni < 4; ++ni) {
#pragma unroll
      for (int r = 0; r < 4; ++r) {
        int row = r0 + wm * 64 + mi * 16 + g * 4 + r;
        int p = p0 + wn * 64 + ni * 16 + l15;
        out[((size_t)b * 512 + row) * 2048 + p] = acc[mi][ni][r] + bo[row];
      }
    }
  }
}

// ---------------------------------------------------------------------------
extern "C" void kernel_launch(void* const* d_in, const int* in_sizes, int n_in,
                              void* d_out, int out_size, void* d_ws, size_t ws_size,
                              hipStream_t stream) {
  (void)in_sizes; (void)n_in; (void)out_size; (void)ws_size;
  const float* Q  = (const float*)d_in[0];
  const float* Wq = (const float*)d_in[1];
  const float* bq = (const float*)d_in[2];
  const float* Wk = (const float*)d_in[3];
  const float* bk = (const float*)d_in[4];
  const float* Wv = (const float*)d_in[5];
  const float* bv = (const float*)d_in[6];
  const float* Wo = (const float*)d_in[7];
  const float* bo = (const float*)d_in[8];
  float* out = (float*)d_out;

  char* ws = (char*)d_ws;
  bf16*  Wf    = (bf16*)(ws + 0);          // 1536*512*2  = 1572864
  bf16*  Wor   = (bf16*)(ws + 1572864);    // 512*512*2   = 524288
  float* biasf = (float*)(ws + 2097152);   // 1536*4      = 6144
  bf16*  Qt    = (bf16*)(ws + 2103296);    // 2*2048*512*2 = 4194304
  bf16*  qp    = (bf16*)(ws + 6297600);    // 4194304
  bf16*  kp    = (bf16*)(ws + 10491904);   // 4194304
  bf16*  vn    = (bf16*)(ws + 14686208);   // 4194304
  bf16*  oh    = (bf16*)(ws + 18880512);   // 4194304  (end ~23.1 MB)

  prep_w<<<dim3(2048), dim3(256), 0, stream>>>(Wq, bq, Wk, bk, Wv, bv, Wo,
                                               Wf, biasf, Wor);
  prep_qt<<<dim3(32, 8, 2), dim3(256), 0, stream>>>(Q, Qt);
  qkv_gemm<<<dim3(12, 16, 2), dim3(256), 0, stream>>>(Wf, Qt, biasf, qp, kp, vn);
  attn_k<<<dim3(32, 8, 2), dim3(256), 0, stream>>>(qp, kp, vn, oh);
  out_gemm<<<dim3(4, 16, 2), dim3(256), 0, stream>>>(Wor, oh, bo, out);
}

// Round 2
// 111.771 us; speedup vs baseline: 1.1083x; 1.1083x over previous
//
#include <hip/hip_runtime.h>

#define DEV __device__ __forceinline__

typedef __bf16 bf16;
typedef __bf16 bf16x8 __attribute__((ext_vector_type(8)));
typedef float f32x4 __attribute__((ext_vector_type(4)));

#define B_ 2
#define D_ 512
#define N_ 2048
#define H_ 8
#define MD_ 64
// 1/sqrt(512) * log2(e): scores pre-scaled so softmax uses exp2 directly
#define SCALE_F (0.04419417382415922f * 1.4426950408889634f)

DEV void gload_lds16(const void* g, void* l) {
  __builtin_amdgcn_global_load_lds(
      (const __attribute__((address_space(1))) void*)g,
      (__attribute__((address_space(3))) void*)l, 16, 0, 0);
}

DEV f32x4 mfma16(bf16x8 a, bf16x8 b, f32x4 c) {
  return __builtin_amdgcn_mfma_f32_16x16x32_bf16(a, b, c, 0, 0, 0);
}

// ---------------------------------------------------------------------------
// prep_w: rows 0..1535 -> Wf bf16 (Wq*SCALE | Wk | Wv), bias_f (bq*SCALE|bk|bv)
//         rows 1536..2047 -> Wo_r[r][h*64+d] = Wo[r][d*8+h]  (bf16)
// ---------------------------------------------------------------------------
__global__ __launch_bounds__(256) void prep_w(
    const float* __restrict__ Wq, const float* __restrict__ bq,
    const float* __restrict__ Wk, const float* __restrict__ bk,
    const float* __restrict__ Wv, const float* __restrict__ bv,
    const float* __restrict__ Wo,
    bf16* __restrict__ Wf, float* __restrict__ biasf, bf16* __restrict__ Wor) {
  int row = blockIdx.x;
  int t = threadIdx.x;
  if (row < 1536) {
    const float* src;
    float scale = 1.0f;
    if (row < 512)       { src = Wq + (size_t)row * 512; scale = SCALE_F; }
    else if (row < 1024) { src = Wk + (size_t)(row - 512) * 512; }
    else                 { src = Wv + (size_t)(row - 1024) * 512; }
    for (int c = t; c < 512; c += 256)
      Wf[(size_t)row * 512 + c] = (bf16)(src[c] * scale);
    if (t == 0) {
      float bb;
      if (row < 512)       bb = bq[row] * SCALE_F;
      else if (row < 1024) bb = bk[row - 512];
      else                 bb = bv[row - 1024];
      biasf[row] = bb;
    }
  } else {
    int r = row - 1536;
    for (int c2 = t; c2 < 512; c2 += 256) {
      int hh = c2 >> 6, dd = c2 & 63;
      Wor[(size_t)r * 512 + c2] = (bf16)Wo[(size_t)r * 512 + dd * 8 + hh];
    }
  }
}

// ---------------------------------------------------------------------------
// prep_qt: Qt[b][n][c] = bf16(Q[b][c][n])   (64x64 tiles through LDS)
// grid (N/64, D/64, B), block 256
// ---------------------------------------------------------------------------
__global__ __launch_bounds__(256) void prep_qt(const float* __restrict__ Q,
                                               bf16* __restrict__ Qt) {
  __shared__ float tile[64][65];
  int b = blockIdx.z;
  int d0 = blockIdx.y * 64;
  int n0 = blockIdx.x * 64;
  int t = threadIdx.x;
  int r = t >> 2, cw = t & 3;

  const float* src = Q + ((size_t)(b * 512 + d0 + r)) * 2048 + n0 + cw * 16;
#pragma unroll
  for (int e4 = 0; e4 < 4; ++e4) {
    float4 v = *(const float4*)(src + e4 * 4);
    tile[r][cw * 16 + e4 * 4 + 0] = v.x;
    tile[r][cw * 16 + e4 * 4 + 1] = v.y;
    tile[r][cw * 16 + e4 * 4 + 2] = v.z;
    tile[r][cw * 16 + e4 * 4 + 3] = v.w;
  }
  __syncthreads();
  bf16x8 o0{}, o1{};
#pragma unroll
  for (int e = 0; e < 8; ++e) {
    o0[e] = (bf16)tile[cw * 16 + e][r];
    o1[e] = (bf16)tile[cw * 16 + 8 + e][r];
  }
  bf16* dst = Qt + ((size_t)(b * 2048 + n0 + r)) * 512 + d0 + cw * 16;
  *(bf16x8*)dst = o0;
  *((bf16x8*)dst + 1) = o1;
}

// ---------------------------------------------------------------------------
// qkv_gemm: C[c][p] = sum_k Wf[c][k] * Qt[b][p][k] + bias[c]
// 128x128 tile, BK=32, 4 waves (2x2), 4x4 frags/wave, global_load_lds staging.
// Epilogue: c<512 -> qp[b][h][p][d]; c<1024 -> kp; else vn[b][c][p]
// grid (12, 16, 2)
// ---------------------------------------------------------------------------
__global__ __launch_bounds__(256) void qkv_gemm(
    const bf16* __restrict__ Wf, const bf16* __restrict__ Qt,
    const float* __restrict__ biasf,
    bf16* __restrict__ qp, bf16* __restrict__ kp, bf16* __restrict__ vn) {
  __shared__ bf16 Al[128 * 32];
  __shared__ bf16 Bl[128 * 32];
  int b = blockIdx.z;
  int c0 = blockIdx.x * 128;
  int p0 = blockIdx.y * 128;
  int tid = threadIdx.x, w = tid >> 6, lane = tid & 63;
  int wm = w >> 1, wn = w & 1;
  int g = lane >> 4, l15 = lane & 15;

  const bf16* Abase = Wf + (size_t)c0 * 512;
  const bf16* Bbase = Qt + ((size_t)b * 2048 + p0) * 512;

  f32x4 acc[4][4] = {};

  for (int ks = 0; ks < 16; ++ks) {
    int k0 = ks * 32;
    __syncthreads();
#pragma unroll
    for (int i = 0; i < 2; ++i) {
      int rowl = w * 32 + i * 16 + (lane >> 2);
      int ch = lane & 3;
      gload_lds16(Abase + (size_t)rowl * 512 + k0 + ch * 8,
                  Al + (w * 32 + i * 16) * 32);
      gload_lds16(Bbase + (size_t)rowl * 512 + k0 + ch * 8,
                  Bl + (w * 32 + i * 16) * 32);
    }
    __syncthreads();
    bf16x8 a[4], bb[4];
#pragma unroll
    for (int mi = 0; mi < 4; ++mi)
      a[mi] = *(const bf16x8*)(Al + (wm * 64 + mi * 16 + l15) * 32 + g * 8);
#pragma unroll
    for (int ni = 0; ni < 4; ++ni)
      bb[ni] = *(const bf16x8*)(Bl + (wn * 64 + ni * 16 + l15) * 32 + g * 8);
#pragma unroll
    for (int mi = 0; mi < 4; ++mi)
#pragma unroll
      for (int ni = 0; ni < 4; ++ni)
        acc[mi][ni] = mfma16(a[mi], bb[ni], acc[mi][ni]);
  }

#pragma unroll
  for (int mi = 0; mi < 4; ++mi) {
#pragma unroll
    for (int ni = 0; ni < 4; ++ni) {
#pragma unroll
      for (int r = 0; r < 4; ++r) {
        int row = c0 + wm * 64 + mi * 16 + g * 4 + r;
        int p = p0 + wn * 64 + ni * 16 + l15;
        float val = acc[mi][ni][r] + biasf[row];
        bf16 hv = (bf16)val;
        if (row < 512) {
          int c = row;
          qp[(((size_t)b * 8 + (c & 7)) * 2048 + p) * 64 + (c >> 3)] = hv;
        } else if (row < 1024) {
          int c = row - 512;
          kp[(((size_t)b * 8 + (c & 7)) * 2048 + p) * 64 + (c >> 3)] = hv;
        } else {
          int c = row - 1024;
          vn[((size_t)b * 512 + c) * 2048 + p] = hv;
        }
      }
    }
  }
}

// ---------------------------------------------------------------------------
// attn_k v2: flash attention per (b,h). Block = 64 queries, 4 waves (16 rows
// each). KV steps of 64. Double-buffered K/V staging: next-step
// global_load_lds issued BEFORE compute, single __syncthreads per step
// (its vmcnt(0) drain lands after compute hides the load latency).
// Softmax: exp2 (scale*log2e folded into Wq), defer-max THR=8, lazy l-sum.
// Ps is wave-private (no barrier needed for it).
// grid (32, 8, 2)
// ---------------------------------------------------------------------------
__global__ __launch_bounds__(256) void attn_k(
    const bf16* __restrict__ qp, const bf16* __restrict__ kp,
    const bf16* __restrict__ vn, bf16* __restrict__ oh) {
  __shared__ bf16 Qs[64 * 64];
  __shared__ bf16 Ks[2][64 * 64];
  __shared__ bf16 Vs[2][64 * 64];
  __shared__ bf16 Ps[64 * 64];
  int b = blockIdx.z, h = blockIdx.y;
  int q0 = blockIdx.x * 64;
  int tid = threadIdx.x, w = tid >> 6, lane = tid & 63;
  int g = lane >> 4, l15 = lane & 15;
  const size_t bh = (size_t)b * 8 + h;

  // per-lane staging coords (swizzled global source, linear LDS dest)
  int srow = w * 16 + (lane >> 3);          // +8 for i=1
  int sch = lane & 7;

  // stage Q once
  const bf16* Qbase = qp + (bh * 2048 + q0) * 64;
#pragma unroll
  for (int i = 0; i < 2; ++i) {
    int row = srow + i * 8;
    int ch = sch ^ (row & 7);
    gload_lds16(Qbase + (size_t)row * 64 + ch * 8, Qs + (w * 16 + i * 8) * 64);
  }

  const bf16* Kall = kp + bh * 2048 * 64;
  const bf16* Vall = vn + ((size_t)(b * 512 + h)) * 2048;

  // stage K/V step 0 into buffer 0
#pragma unroll
  for (int i = 0; i < 2; ++i) {
    int row = srow + i * 8;
    int ch = sch ^ (row & 7);
    gload_lds16(Kall + (size_t)row * 64 + ch * 8, Ks[0] + (w * 16 + i * 8) * 64);
    gload_lds16(Vall + (size_t)row * 16384 + ch * 8, Vs[0] + (w * 16 + i * 8) * 64);
  }

  f32x4 oacc[4] = {};
  float mrow[4], rs_acc[4];
#pragma unroll
  for (int r = 0; r < 4; ++r) { mrow[r] = -1e30f; rs_acc[r] = 0.0f; }

  int irow = w * 16 + l15;

  __syncthreads();  // step-0 staging drained (vmcnt(0) inside)

  for (int t = 0; t < 32; ++t) {
    int cur = t & 1, nxt = cur ^ 1;
    int tn = (t < 31) ? t + 1 : 31;  // clamp (redundant last prefetch)

    // issue next-step staging (lands during compute; drained at loop-end sync)
    const bf16* Kbase = Kall + (size_t)tn * 64 * 64;
    const bf16* Vbase = Vall + (size_t)tn * 64;
#pragma unroll
    for (int i = 0; i < 2; ++i) {
      int row = srow + i * 8;
      int ch = sch ^ (row & 7);
      gload_lds16(Kbase + (size_t)row * 64 + ch * 8,
                  Ks[nxt] + (w * 16 + i * 8) * 64);
      gload_lds16(Vbase + (size_t)row * 16384 + ch * 8,
                  Vs[nxt] + (w * 16 + i * 8) * 64);
    }

    // S = Q K^T for this wave's 16-row strip (scale+log2e pre-folded into q)
    f32x4 s[4] = {};
#pragma unroll
    for (int ks2 = 0; ks2 < 2; ++ks2) {
      bf16x8 qa = *(const bf16x8*)(Qs + irow * 64 + (((ks2 * 4 + g) ^ (irow & 7)) << 3));
#pragma unroll
      for (int jt = 0; jt < 4; ++jt) {
        int jrow = jt * 16 + l15;
        bf16x8 kb = *(const bf16x8*)(Ks[cur] + jrow * 64 + (((ks2 * 4 + g) ^ (jrow & 7)) << 3));
        s[jt] = mfma16(qa, kb, s[jt]);
      }
    }

    // online softmax with defer-max (THR=8): row = g*4+r, cols across l15
    float nm[4];
    float grow = -1e30f;
#pragma unroll
    for (int r = 0; r < 4; ++r) {
      float rm = fmaxf(fmaxf(s[0][r], s[1][r]), fmaxf(s[2][r], s[3][r]));
      rm = fmaxf(rm, __shfl_xor(rm, 1));
      rm = fmaxf(rm, __shfl_xor(rm, 2));
      rm = fmaxf(rm, __shfl_xor(rm, 4));
      rm = fmaxf(rm, __shfl_xor(rm, 8));
      nm[r] = fmaxf(mrow[r], rm);
      grow = fmaxf(grow, rm - mrow[r]);
    }
    if (__any(grow > 8.0f)) {
#pragma unroll
      for (int r = 0; r < 4; ++r) {
        float esc = __builtin_amdgcn_exp2f(mrow[r] - nm[r]);
        mrow[r] = nm[r];
        rs_acc[r] *= esc;
#pragma unroll
        for (int dt = 0; dt < 4; ++dt) oacc[dt][r] *= esc;
      }
    }
#pragma unroll
    for (int jt = 0; jt < 4; ++jt) {
#pragma unroll
      for (int r = 0; r < 4; ++r) {
        float pv = __builtin_amdgcn_exp2f(s[jt][r] - mrow[r]);
        rs_acc[r] += pv;  // per-lane partial; reduced once at the end
        int iw = w * 16 + g * 4 + r;
        int j = jt * 16 + l15;
        Ps[iw * 64 + (j ^ ((iw & 7) << 3))] = (bf16)pv;
      }
    }

    // O += P V   (Ps is wave-private: lgkmcnt ordering only, no barrier)
#pragma unroll
    for (int ks2 = 0; ks2 < 2; ++ks2) {
      bf16x8 pa = *(const bf16x8*)(Ps + irow * 64 + (((ks2 * 4 + g) ^ (irow & 7)) << 3));
#pragma unroll
      for (int dt = 0; dt < 4; ++dt) {
        int drow = dt * 16 + l15;
        bf16x8 vb = *(const bf16x8*)(Vs[cur] + drow * 64 + (((ks2 * 4 + g) ^ (drow & 7)) << 3));
        oacc[dt] = mfma16(pa, vb, oacc[dt]);
      }
    }

    __syncthreads();  // drains next-step staging + releases buf[cur] for reuse
  }

  // final l: reduce per-lane partials across the 16-lane row groups
  float lrow[4];
#pragma unroll
  for (int r = 0; r < 4; ++r) {
    float t2 = rs_acc[r];
    t2 += __shfl_xor(t2, 1);
    t2 += __shfl_xor(t2, 2);
    t2 += __shfl_xor(t2, 4);
    t2 += __shfl_xor(t2, 8);
    lrow[r] = t2;
  }

  // epilogue: normalize and store oh[b][h][p][d]
#pragma unroll
  for (int dt = 0; dt < 4; ++dt) {
#pragma unroll
    for (int r = 0; r < 4; ++r) {
      int i = w * 16 + g * 4 + r;
      float inv = 1.0f / lrow[r];
      oh[(bh * 2048 + q0 + i) * 64 + dt * 16 + l15] = (bf16)(oacc[dt][r] * inv);
    }
  }
}

// ---------------------------------------------------------------------------
// out_gemm: out[b][r][p] = sum_k Wor[r][k] * oh_as_B[p][k] + bo[r]   (fp32 out)
// k = h*64+d ; B row p slice for k-step lives at oh[b][h][p0+row][d0..d0+31]
// grid (4, 16, 2)
// ---------------------------------------------------------------------------
__global__ __launch_bounds__(256) void out_gemm(
    const bf16* __restrict__ Wor, const bf16* __restrict__ oh,
    const float* __restrict__ bo, float* __restrict__ out) {
  __shared__ bf16 Al[128 * 32];
  __shared__ bf16 Bl[128 * 32];
  int b = blockIdx.z;
  int r0 = blockIdx.x * 128;
  int p0 = blockIdx.y * 128;
  int tid = threadIdx.x, w = tid >> 6, lane = tid & 63;
  int wm = w >> 1, wn = w & 1;
  int g = lane >> 4, l15 = lane & 15;

  const bf16* Abase = Wor + (size_t)r0 * 512;

  f32x4 acc[4][4] = {};

  for (int ks = 0; ks < 16; ++ks) {
    int k0 = ks * 32;
    int hh = k0 >> 6, d0 = k0 & 63;
    const bf16* Bbase = oh + (((size_t)b * 8 + hh) * 2048 + p0) * 64 + d0;
    __syncthreads();
#pragma unroll
    for (int i = 0; i < 2; ++i) {
      int rowl = w * 32 + i * 16 + (lane >> 2);
      int ch = lane & 3;
      gload_lds16(Abase + (size_t)rowl * 512 + k0 + ch * 8,
                  Al + (w * 32 + i * 16) * 32);
      gload_lds16(Bbase + (size_t)rowl * 64 + ch * 8,
                  Bl + (w * 32 + i * 16) * 32);
    }
    __syncthreads();
    bf16x8 a[4], bb[4];
#pragma unroll
    for (int mi = 0; mi < 4; ++mi)
      a[mi] = *(const bf16x8*)(Al + (wm * 64 + mi * 16 + l15) * 32 + g * 8);
#pragma unroll
    for (int ni = 0; ni < 4; ++ni)
      bb[ni] = *(const bf16x8*)(Bl + (wn * 64 + ni * 16 + l15) * 32 + g * 8);
#pragma unroll
    for (int mi = 0; mi < 4; ++mi)
#pragma unroll
      for (int ni = 0; ni < 4; ++ni)
        acc[mi][ni] = mfma16(a[mi], bb[ni], acc[mi][ni]);
  }

#pragma unroll
  for (int mi = 0; mi < 4; ++mi) {
#pragma unroll
    for (int ni = 0; ni < 4; ++ni) {
#pragma unroll
      for (int r = 0; r < 4; ++r) {
        int row = r0 + wm * 64 + mi * 16 + g * 4 + r;
        int p = p0 + wn * 64 + ni * 16 + l15;
        out[((size_t)b * 512 + row) * 2048 + p] = acc[mi][ni][r] + bo[row];
      }
    }
  }
}

// ---------------------------------------------------------------------------
extern "C" void kernel_launch(void* const* d_in, const int* in_sizes, int n_in,
                              void* d_out, int out_size, void* d_ws, size_t ws_size,
                              hipStream_t stream) {
  (void)in_sizes; (void)n_in; (void)out_size; (void)ws_size;
  const float* Q  = (const float*)d_in[0];
  const float* Wq = (const float*)d_in[1];
  const float* bq = (const float*)d_in[2];
  const float* Wk = (const float*)d_in[3];
  const float* bk = (const float*)d_in[4];
  const float* Wv = (const float*)d_in[5];
  const float* bv = (const float*)d_in[6];
  const float* Wo = (const float*)d_in[7];
  const float* bo = (const float*)d_in[8];
  float* out = (float*)d_out;

  char* ws = (char*)d_ws;
  bf16*  Wf    = (bf16*)(ws + 0);          // 1536*512*2  = 1572864
  bf16*  Wor   = (bf16*)(ws + 1572864);    // 512*512*2   = 524288
  float* biasf = (float*)(ws + 2097152);   // 1536*4      = 6144
  bf16*  Qt    = (bf16*)(ws + 2103296);    // 2*2048*512*2 = 4194304
  bf16*  qp    = (bf16*)(ws + 6297600);    // 4194304
  bf16*  kp    = (bf16*)(ws + 10491904);   // 4194304
  bf16*  vn    = (bf16*)(ws + 14686208);   // 4194304
  bf16*  oh    = (bf16*)(ws + 18880512);   // 4194304  (end ~23.1 MB)

  prep_w<<<dim3(2048), dim3(256), 0, stream>>>(Wq, bq, Wk, bk, Wv, bv, Wo,
                                               Wf, biasf, Wor);
  prep_qt<<<dim3(32, 8, 2), dim3(256), 0, stream>>>(Q, Qt);
  qkv_gemm<<<dim3(12, 16, 2), dim3(256), 0, stream>>>(Wf, Qt, biasf, qp, kp, vn);
  attn_k<<<dim3(32, 8, 2), dim3(256), 0, stream>>>(qp, kp, vn, oh);
  out_gemm<<<dim3(4, 16, 2), dim3(256), 0, stream>>>(Wor, oh, bo, out);
}